// Round 10
// baseline (27.475 us; speedup 1.0000x reference)
//
#include <hip/hip_runtime.h>

// ColBERT maxsim via MFMA + masked-row compaction, single-batch staging.
// out[b] = sum_q max_k ( mask[b,k] ? <D[b,k,:], Q[b/8,q,:]> : -9999 )
// B*NWAY=1024 docs, DLEN=220, QLEN=32, DIM=128.
//
// Round-9 lesson: two 8-deep staging batches drain the vmem queue at the half
// boundary (~900cy re-pay), and the one-round grid (1024 blocks, 4/CU) phases
// prologue/stage/compute globally -> HBM idles at the seams. Round-10:
// 512-thread blocks (8 waves), 1 doc/block, 2 blocks/CU, TWO block-rounds:
//  - per-thread staging = ONE fully-unrolled <=8-deep batch (no mid drain);
//  - round-2 blocks' prologues overlap round-1 computes (phase stagger);
//  - waves 0-3 compute one 32-row tile each; waves 4-7 stage + reduce only.
//
// Compaction (R8, exact): masked rows never win the max (-9999); compact kept
// row indices, stage only those (~110 of 220) -> D HBM 115->58 MB.
// XOR swizzle byte ^= ((row&7)<<4) on 256B bf16 LDS rows kills the 32-way
// ds_read_b128 bank conflict. Q: direct strided loads (R7: staging Q = null).
// MFMA mfma_f32_32x32x16_bf16; same k-map for A and B => layout-safe.
// C/D layout (m74/m101): col(q)=lane&31, row(token)=(reg&3)+8*(reg>>2)+4*g.

#define QLEN   32
#define DIM    128
#define DLEN   220
#define NWAVES 8
#define NTHR   512
#define C0MAX  128

typedef __attribute__((ext_vector_type(8)))  short bf16x8;
typedef __attribute__((ext_vector_type(16))) float f32x16;

__device__ __forceinline__ short f2bf(float f) {
    __bf16 h = (__bf16)f;                      // RNE hardware convert
    return __builtin_bit_cast(short, h);
}

__device__ __forceinline__ short4 cvt4(const float4& v) {
    short4 s;
    s.x = f2bf(v.x); s.y = f2bf(v.y); s.z = f2bf(v.z); s.w = f2bf(v.w);
    return s;
}

__device__ __forceinline__ bf16x8 cvt8(const float4& a, const float4& b) {
    bf16x8 r;
    r[0] = f2bf(a.x); r[1] = f2bf(a.y); r[2] = f2bf(a.z); r[3] = f2bf(a.w);
    r[4] = f2bf(b.x); r[5] = f2bf(b.y); r[6] = f2bf(b.z); r[7] = f2bf(b.w);
    return r;
}

__global__ __launch_bounds__(NTHR, 4)   // 4 waves/SIMD = 2 blocks/CU, 128 VGPR cap
void colbert_mfma(const float* __restrict__ Q,
                  const float* __restrict__ D,
                  const int*   __restrict__ Dm,
                  float* __restrict__ out)
{
    // XCD swizzle (bijective: gridDim.x = 1024 % 8 == 0): docs sharing a Q
    // tile land on one XCD's L2.
    const int cpx = gridDim.x >> 3;
    const int o   = blockIdx.x;
    const int b   = (o & 7) * cpx + (o >> 3);

    const int tid  = threadIdx.x;
    const int wave = tid >> 6;
    const int lane = tid & 63;
    const int qb   = b >> 3;            // nway = 8

    const int col = lane & 31;          // A row-in-tile / B col (q)
    const int g   = lane >> 5;          // k-group

    __shared__ __align__(16) short dl[C0MAX * DIM];   // 32 KB staged bf16 rows
    __shared__ short list[DLEN + 4];                   // compacted row indices
    __shared__ int   wcnt[NWAVES];
    __shared__ int   s_nc;
    __shared__ float red[NWAVES][QLEN];

    const float* __restrict__ dbase = D + (size_t)b * DLEN * DIM;

    // ---- 1. mask load FIRST: heads the dependency chain ----
    int mv = 0;
    if (tid < DLEN) mv = Dm[(size_t)b * DLEN + tid];

    // ---- 2. Q loads issued under the mask latency ----
    const float* __restrict__ qrow = Q + ((size_t)qb * QLEN + col) * DIM;
    float4 qx[8], qy[8];
#pragma unroll
    for (int ks = 0; ks < 8; ++ks) {
        qx[ks] = *reinterpret_cast<const float4*>(qrow + ks * 16 + g * 8);
        qy[ks] = *reinterpret_cast<const float4*>(qrow + ks * 16 + g * 8 + 4);
    }

    // ---- 3. compact kept row indices (order-preserving) ----
    const unsigned long long bal = __ballot(mv > 0);
    const int prefix = __popcll(bal & ((1ull << lane) - 1ull));
    if (lane == 0) wcnt[wave] = __popcll(bal);
    __syncthreads();
    int base = 0;
#pragma unroll
    for (int w = 0; w < NWAVES; ++w) base += (w < wave) ? wcnt[w] : 0;
    if (mv > 0) list[base + prefix] = (short)tid;
    if (tid == 0) {
        int t = 0;
#pragma unroll
        for (int w = 0; w < NWAVES; ++w) t += wcnt[w];
        s_nc = t;
    }

    // Q cvt overlaps the compaction barrier (frees 64 VGPR before D staging)
    bf16x8 bq[8];
#pragma unroll
    for (int ks = 0; ks < 8; ++ks) bq[ks] = cvt8(qx[ks], qy[ks]);
    __syncthreads();

    const int nc = s_nc;                 // kept rows, ~Binom(220,1/2) ~ 110
    const int c0 = (nc < C0MAX) ? nc : C0MAX;

    float best = -9999.0f;

    if (c0 > 0) {
        const int nch = c0 * 32;         // 16B chunks in chunk0 (<= 4096)

        // ---- 4. indices->regs, then ONE fully-unrolled <=8-deep batch ----
        short rrow[8];
#pragma unroll
        for (int u = 0; u < 8; ++u) {
            const int c = tid + u * NTHR;
            rrow[u] = list[(c < nch ? c : 0) >> 5];
        }
        float4 v[8];
#pragma unroll
        for (int u = 0; u < 8; ++u) {                 // dense 8-deep issue
            const int cir = (tid + u * NTHR) & 31;
            v[u] = *reinterpret_cast<const float4*>(
                       dbase + (size_t)rrow[u] * DIM + cir * 4);
        }
#pragma unroll
        for (int u = 0; u < 8; ++u) {                 // predicated writes
            const int c = tid + u * NTHR;
            if (c < nch) {
                const int lr = c >> 5, cir = c & 31;
                const int byte = lr * 256 + ((cir * 8) ^ ((lr & 7) << 4));
                *reinterpret_cast<short4*>(reinterpret_cast<char*>(dl) + byte)
                    = cvt4(v[u]);
            }
        }
        __syncthreads();

        // ---- 5. compute chunk0: ceil(c0/32) tiles on waves 0-3 ----
        const int ntiles = (c0 + 31) >> 5;
        if (wave < ntiles) {
            const int tloc = wave * 32;
            int rloc = tloc + col;
            if (rloc >= c0) rloc = 0;              // clamp; rejected below
            const int rsw = (rloc & 7) << 4;
            f32x16 acc = {};
#pragma unroll
            for (int ks = 0; ks < 8; ++ks) {
                const int byte = rloc * 256 + ((ks * 32 + g * 16) ^ rsw);
                const bf16x8 a = *reinterpret_cast<const bf16x8*>(
                                     reinterpret_cast<const char*>(dl) + byte);
                acc = __builtin_amdgcn_mfma_f32_32x32x16_bf16(a, bq[ks], acc, 0, 0, 0);
            }
            // validity: compacted local index < c0 (mask already applied)
#pragma unroll
            for (int p = 0; p < 4; ++p) {
                const int i4 = tloc + p * 8 + g * 4;
                const float v0 = (i4 + 0 < c0) ? acc[4 * p + 0] : -9999.0f;
                const float v1 = (i4 + 1 < c0) ? acc[4 * p + 1] : -9999.0f;
                const float v2 = (i4 + 2 < c0) ? acc[4 * p + 2] : -9999.0f;
                const float v3 = (i4 + 3 < c0) ? acc[4 * p + 3] : -9999.0f;
                best = fmaxf(best, fmaxf(fmaxf(v0, v1), fmaxf(v2, v3)));
            }
        }
    }

    // ---- rare chunk1 (nc > 128; ~0.7% of docs): simple rolled flow ----
    const int cr1 = nc - c0;
    if (cr1 > 0) {
        __syncthreads();                 // chunk0 reads done before overwrite
        const int nch = cr1 * 32;
        for (int i = tid; i < nch; i += NTHR) {
            const int row = list[c0 + (i >> 5)], cir = i & 31;
            const float4 vv = *reinterpret_cast<const float4*>(
                                  dbase + (size_t)row * DIM + cir * 4);
            const int lr = i >> 5;
            const int byte = lr * 256 + ((cir * 8) ^ ((lr & 7) << 4));
            *reinterpret_cast<short4*>(reinterpret_cast<char*>(dl) + byte) = cvt4(vv);
        }
        __syncthreads();

        const int ntiles = (cr1 + 31) >> 5;
        if (wave < ntiles) {
            const int tloc = wave * 32;
            int rloc = tloc + col;
            if (rloc >= cr1) rloc = 0;
            const int rsw = (rloc & 7) << 4;
            f32x16 acc = {};
#pragma unroll
            for (int ks = 0; ks < 8; ++ks) {
                const int byte = rloc * 256 + ((ks * 32 + g * 16) ^ rsw);
                const bf16x8 a = *reinterpret_cast<const bf16x8*>(
                                     reinterpret_cast<const char*>(dl) + byte);
                acc = __builtin_amdgcn_mfma_f32_32x32x16_bf16(a, bq[ks], acc, 0, 0, 0);
            }
#pragma unroll
            for (int p = 0; p < 4; ++p) {
                const int i4 = tloc + p * 8 + g * 4;
                const float v0 = (i4 + 0 < cr1) ? acc[4 * p + 0] : -9999.0f;
                const float v1 = (i4 + 1 < cr1) ? acc[4 * p + 1] : -9999.0f;
                const float v2 = (i4 + 2 < cr1) ? acc[4 * p + 2] : -9999.0f;
                const float v3 = (i4 + 3 < cr1) ? acc[4 * p + 3] : -9999.0f;
                best = fmaxf(best, fmaxf(fmaxf(v0, v1), fmaxf(v2, v3)));
            }
        }
    }

    // combine the two k-group token-halves (lanes l and l^32 share q=col)
    best = fmaxf(best, __shfl_xor(best, 32, 64));

    // ---- cross-wave max (waves 4-7 contribute -9999), then sum over q ----
    if (lane < 32) red[wave][col] = best;
    __syncthreads();

    if (tid < QLEN) {
        float m = red[0][tid];
#pragma unroll
        for (int w = 1; w < NWAVES; ++w) m = fmaxf(m, red[w][tid]);
#pragma unroll
        for (int off = 16; off > 0; off >>= 1) m += __shfl_xor(m, off, 32);
        if (tid == 0) out[b] = m;
    }
}

extern "C" void kernel_launch(void* const* d_in, const int* in_sizes, int n_in,
                              void* d_out, int out_size, void* d_ws, size_t ws_size,
                              hipStream_t stream)
{
    const float* Q  = (const float*)d_in[0];
    const float* D  = (const float*)d_in[1];
    const int*   Dm = (const int*)d_in[2];
    float* outp = (float*)d_out;
    const int ndocs = out_size;   // B*NWAY = 1024
    colbert_mfma<<<ndocs, NTHR, 0, stream>>>(Q, D, Dm, outp);
}

// Round 11
// 21.941 us; speedup vs baseline: 1.2522x; 1.2522x over previous
//
#include <hip/hip_runtime.h>

// ColBERT maxsim via MFMA + masked-row compaction + DIRECT gather fragments.
// out[b] = sum_q max_k ( mask[b,k] ? <D[b,k,:], Q[b/8,q,:]> : -9999 )
// B*NWAY=1024 docs, DLEN=220, QLEN=32, DIM=128.
//
// Round-10 lesson: 2 big blocks/CU < 4 small blocks/CU (phase diversity).
// Round-11: keep R8 compaction (bytes 115->58 MB, exact: masked rows never
// win the max) but DROP the LDS staging pipeline entirely. R4 proved the
// direct global->reg fragment gather (16B/lane @ 512B stride) sustains
// ~4.0 TB/s effective with 4 blocks/CU; R9's stage->barrier->compute chain
// only reached ~3.1 TB/s on compacted bytes. Gather kept rows directly:
// row = list[tile*32 + col], 16 float4 loads per tile per lane (deep queue,
// no barriers after compaction, every wave computes, one uniform path for
// any nc via tiles {wave, wave+4}).
//
// MFMA mfma_f32_32x32x16_bf16; same k-map (k = ks*16 + g*8 + j) for A and B
// => layout-safe (dot products K-permutation invariant).
// C/D layout (m74/m101): col(q)=lane&31, row(token)=(reg&3)+8*(reg>>2)+4*g.

#define QLEN   32
#define DIM    128
#define DLEN   220
#define NWAVES 4

typedef __attribute__((ext_vector_type(8)))  short bf16x8;
typedef __attribute__((ext_vector_type(16))) float f32x16;

__device__ __forceinline__ short f2bf(float f) {
    __bf16 h = (__bf16)f;                      // RNE hardware convert
    return __builtin_bit_cast(short, h);
}

__device__ __forceinline__ bf16x8 cvt8(const float4& a, const float4& b) {
    bf16x8 r;
    r[0] = f2bf(a.x); r[1] = f2bf(a.y); r[2] = f2bf(a.z); r[3] = f2bf(a.w);
    r[4] = f2bf(b.x); r[5] = f2bf(b.y); r[6] = f2bf(b.z); r[7] = f2bf(b.w);
    return r;
}

__global__ __launch_bounds__(256, 4)
void colbert_mfma(const float* __restrict__ Q,
                  const float* __restrict__ D,
                  const int*   __restrict__ Dm,
                  float* __restrict__ out)
{
    // XCD swizzle (bijective: gridDim.x = 1024 % 8 == 0): docs sharing a Q
    // tile land on one XCD's L2.
    const int cpx = gridDim.x >> 3;
    const int o   = blockIdx.x;
    const int b   = (o & 7) * cpx + (o >> 3);

    const int tid  = threadIdx.x;
    const int wave = tid >> 6;
    const int lane = tid & 63;
    const int qb   = b >> 3;            // nway = 8

    const int col = lane & 31;          // A row-in-tile / B col (q)
    const int g   = lane >> 5;          // k-group

    __shared__ short list[DLEN + 4];    // compacted kept-row indices
    __shared__ int   wcnt[NWAVES];
    __shared__ int   s_nc;
    __shared__ float red[NWAVES][QLEN];

    const float* __restrict__ dbase = D + (size_t)b * DLEN * DIM;

    // ---- 1. mask load FIRST: heads the dependency chain ----
    int mv = 0;
    if (tid < DLEN) mv = Dm[(size_t)b * DLEN + tid];

    // ---- 2. Q loads issued under the mask latency ----
    const float* __restrict__ qrow = Q + ((size_t)qb * QLEN + col) * DIM;
    float4 qx[8], qy[8];
#pragma unroll
    for (int ks = 0; ks < 8; ++ks) {
        qx[ks] = *reinterpret_cast<const float4*>(qrow + ks * 16 + g * 8);
        qy[ks] = *reinterpret_cast<const float4*>(qrow + ks * 16 + g * 8 + 4);
    }

    // ---- 3. compact kept row indices (order-preserving) ----
    const unsigned long long bal = __ballot(mv > 0);
    const int prefix = __popcll(bal & ((1ull << lane) - 1ull));
    if (lane == 0) wcnt[wave] = __popcll(bal);
    __syncthreads();
    int base = 0;
#pragma unroll
    for (int w = 0; w < NWAVES; ++w) base += (w < wave) ? wcnt[w] : 0;
    if (mv > 0) list[base + prefix] = (short)tid;
    if (tid == 0) s_nc = wcnt[0] + wcnt[1] + wcnt[2] + wcnt[3];

    // Q cvt overlaps the compaction barrier
    bf16x8 bq[8];
#pragma unroll
    for (int ks = 0; ks < 8; ++ks) bq[ks] = cvt8(qx[ks], qy[ks]);
    __syncthreads();

    const int nc = s_nc;                // kept rows, ~Binom(220,1/2) ~ 110
    float best = -9999.0f;

    // ---- 4. per-tile direct gather + MFMA; tiles {wave, wave+4} cover any nc ----
#pragma unroll
    for (int tt = 0; tt < 2; ++tt) {
        const int tile = wave + tt * NWAVES;    // block-uniform branch below
        const int tb   = tile * 32;
        if (tb < nc) {
            int li = tb + col;
            if (li >= nc) li = nc - 1;          // clamp; rejected in epilogue
            const int row = list[li];
            const float* __restrict__ drow = dbase + (size_t)row * DIM;

            // 16-deep load queue per lane (full kept row, 512 B)
            float4 af[16];
#pragma unroll
            for (int ks = 0; ks < 8; ++ks) {
                af[2 * ks]     = *reinterpret_cast<const float4*>(drow + ks * 16 + g * 8);
                af[2 * ks + 1] = *reinterpret_cast<const float4*>(drow + ks * 16 + g * 8 + 4);
            }

            f32x16 acc = {};
#pragma unroll
            for (int ks = 0; ks < 8; ++ks) {
                const bf16x8 a = cvt8(af[2 * ks], af[2 * ks + 1]);
                acc = __builtin_amdgcn_mfma_f32_32x32x16_bf16(a, bq[ks], acc, 0, 0, 0);
            }

            // validity: compacted local index < nc (mask already applied)
            // lane's acc reg r covers local idx tb + (r&3) + 8*(r>>2) + 4*g
#pragma unroll
            for (int p = 0; p < 4; ++p) {
                const int i4 = tb + p * 8 + g * 4;
                const float v0 = (i4 + 0 < nc) ? acc[4 * p + 0] : -9999.0f;
                const float v1 = (i4 + 1 < nc) ? acc[4 * p + 1] : -9999.0f;
                const float v2 = (i4 + 2 < nc) ? acc[4 * p + 2] : -9999.0f;
                const float v3 = (i4 + 3 < nc) ? acc[4 * p + 3] : -9999.0f;
                best = fmaxf(best, fmaxf(fmaxf(v0, v1), fmaxf(v2, v3)));
            }
        }
    }

    // combine the two k-group token-halves (lanes l and l^32 share q=col)
    best = fmaxf(best, __shfl_xor(best, 32, 64));

    // ---- cross-wave max, then sum over q ----
    if (lane < 32) red[wave][col] = best;
    __syncthreads();

    if (tid < QLEN) {
        float m = red[0][tid];
#pragma unroll
        for (int w = 1; w < NWAVES; ++w) m = fmaxf(m, red[w][tid]);
#pragma unroll
        for (int off = 16; off > 0; off >>= 1) m += __shfl_xor(m, off, 32);
        if (tid == 0) out[b] = m;
    }
}

extern "C" void kernel_launch(void* const* d_in, const int* in_sizes, int n_in,
                              void* d_out, int out_size, void* d_ws, size_t ws_size,
                              hipStream_t stream)
{
    const float* Q  = (const float*)d_in[0];
    const float* D  = (const float*)d_in[1];
    const int*   Dm = (const int*)d_in[2];
    float* outp = (float*)d_out;
    const int ndocs = out_size;   // B*NWAY = 1024
    colbert_mfma<<<ndocs, NWAVES * 64, 0, stream>>>(Q, D, Dm, outp);
}